// Round 5
// baseline (142.508 us; speedup 1.0000x reference)
//
#include <hip/hip_runtime.h>

#define DM 1024
#define NH 16
#define DK 64
#define BB 2
#define SS 2048
#define MT (BB*SS)   // 4096 rows

typedef __attribute__((ext_vector_type(8))) short bf16x8;
typedef __attribute__((ext_vector_type(4))) float f32x4;

#define QSCALE 0.1803368801111191f   /* 0.125 * log2(e) */
#define EXPC  (-14.426950408889634f) /* -10 * log2(e)    */

__device__ __forceinline__ unsigned short f2bf(float f) {
    unsigned int u = __float_as_uint(f);
    u += 0x7FFF + ((u >> 16) & 1);          // round-to-nearest-even
    return (unsigned short)(u >> 16);
}

__device__ __forceinline__ unsigned int cvt_pk_bf16(float lo, float hi) {
    unsigned int r;
    asm("v_cvt_pk_bf16_f32 %0, %1, %2" : "=v"(r) : "v"(lo), "v"(hi));
    return r;
}

// async global->LDS, 16B per lane; LDS dest is wave-uniform base + lane*16
__device__ __forceinline__ void gload16(const void* g, void* l) {
    __builtin_amdgcn_global_load_lds(
        (const __attribute__((address_space(1))) unsigned int*)g,
        (__attribute__((address_space(3))) unsigned int*)(unsigned int)(unsigned long long)l,
        16, 0, 0);
}

// ---------------------------------------------------------------------------
// fp32 -> bf16 bulk converter (with per-array scale; wq/bq absorb softmax scale)
// ---------------------------------------------------------------------------
struct CvtArgs {
    const float* s[7];
    unsigned short* d[7];
    int n[7];
    float scl[7];
};

__global__ __launch_bounds__(256) void cvt_f32_bf16(CvtArgs a) {
    const int arr = blockIdx.y;
    const int i = (blockIdx.x * 256 + threadIdx.x) * 8;
    if (i >= a.n[arr]) return;
    const float sc = a.scl[arr];
    const float4* sp = (const float4*)(a.s[arr] + i);
    float4 x = sp[0], y = sp[1];
    union { unsigned short us[8]; uint4 u4; } r;
    r.us[0] = f2bf(x.x * sc); r.us[1] = f2bf(x.y * sc);
    r.us[2] = f2bf(x.z * sc); r.us[3] = f2bf(x.w * sc);
    r.us[4] = f2bf(y.x * sc); r.us[5] = f2bf(y.y * sc);
    r.us[6] = f2bf(y.z * sc); r.us[7] = f2bf(y.w * sc);
    *(uint4*)(a.d[arr] + i) = r.u4;
}

// ---------------------------------------------------------------------------
// Merged Q/K/V projection GEMM, double-buffered staging (stage k+1 before
// compute k; __syncthreads drains). grid=(256,3). Tiles/layout as before.
// ---------------------------------------------------------------------------
struct ProjArgs {
    const unsigned short* A[3];
    const unsigned short* B[3];
    const float* bias[3];
    unsigned short* out[3];
    float bscale[3];
};

__global__ __launch_bounds__(256, 3) void proj3(ProjArgs pa) {
    __shared__ __align__(16) unsigned short As[2][128 * 32];
    __shared__ __align__(16) unsigned short Bs[2][128 * 32];

    const int z = blockIdx.y;
    const int bx = blockIdx.x;
    const int m0 = (z < 2 ? (bx >> 3) : (bx >> 5)) * 128;
    const int n0 = (z < 2 ? (bx & 7) : (bx & 31)) * 128;
    const unsigned short* A = pa.A[z];
    const unsigned short* B = pa.B[z];
    const float* bias = pa.bias[z];
    const float bsc = pa.bscale[z];
    unsigned short* out = pa.out[z];

    const int tid = (int)threadIdx.x;
    const int l = tid & 63;
    const int w = tid >> 6;
    const int wm = w >> 1, wn = w & 1;

    const int strow = l >> 2;
    const int sslot = (l & 3) ^ ((l >> 3) & 3);
    const int fr = l & 15, fj = l >> 4;
    const int swz = ((fj ^ ((fr >> 1) & 3)) << 4);

    const f32x4 zero = {0.f, 0.f, 0.f, 0.f};
    f32x4 acc[4][4];
    #pragma unroll
    for (int mf = 0; mf < 4; ++mf)
        #pragma unroll
        for (int nf = 0; nf < 4; ++nf) acc[mf][nf] = zero;

    // prologue: stage kt=0 into buf 0
    #pragma unroll
    for (int t = 0; t < 2; ++t) {
        const int c = w * 2 + t;
        const int row = c * 16 + strow;
        gload16(A + (size_t)(m0 + row) * DM + sslot * 8, (char*)As[0] + c * 1024);
        gload16(B + (size_t)(n0 + row) * DM + sslot * 8, (char*)Bs[0] + c * 1024);
    }
    __syncthreads();

    for (int kt = 0; kt < DM; kt += 32) {
        const int cb = (kt >> 5) & 1;
        if (kt + 32 < DM) {
            #pragma unroll
            for (int t = 0; t < 2; ++t) {
                const int c = w * 2 + t;
                const int row = c * 16 + strow;
                gload16(A + (size_t)(m0 + row) * DM + (kt + 32) + sslot * 8, (char*)As[cb ^ 1] + c * 1024);
                gload16(B + (size_t)(n0 + row) * DM + (kt + 32) + sslot * 8, (char*)Bs[cb ^ 1] + c * 1024);
            }
        }
        bf16x8 af[4], bfr[4];
        #pragma unroll
        for (int mf = 0; mf < 4; ++mf)
            af[mf] = *(const bf16x8*)((const char*)As[cb] + (wm * 64 + mf * 16 + fr) * 64 + swz);
        #pragma unroll
        for (int nf = 0; nf < 4; ++nf)
            bfr[nf] = *(const bf16x8*)((const char*)Bs[cb] + (wn * 64 + nf * 16 + fr) * 64 + swz);
        #pragma unroll
        for (int mf = 0; mf < 4; ++mf)
            #pragma unroll
            for (int nf = 0; nf < 4; ++nf)
                acc[mf][nf] = __builtin_amdgcn_mfma_f32_16x16x32_bf16(af[mf], bfr[nf], acc[mf][nf], 0, 0, 0);
        __syncthreads();   // drains this iter's stage (next buf) + WAR on cb
    }

    #pragma unroll
    for (int nf = 0; nf < 4; ++nf) {
        const int n = n0 + wn * 64 + nf * 16 + fr;
        const float bn = (z == 2) ? 0.f : bias[n] * bsc;
        #pragma unroll
        for (int mf = 0; mf < 4; ++mf) {
            #pragma unroll
            for (int j = 0; j < 4; ++j) {
                const int m = m0 + wm * 64 + mf * 16 + fj * 4 + j;
                if (z < 2) {
                    const float val = acc[mf][nf][j] + bn;
                    out[((size_t)((m >> 11) * NH + (n >> 6)) * SS + (m & (SS - 1))) * DK + (n & 63)] = f2bf(val);
                } else {
                    const float val = acc[mf][nf][j] + bias[m];
                    out[(size_t)((n >> 11) * NH + (m >> 6)) * (SS * DK) + (size_t)(m & 63) * SS + (n & (SS - 1))] = f2bf(val);
                }
            }
        }
    }
}

// ---------------------------------------------------------------------------
// Output projection, double-buffered staging. 128x64 tile, grid 32x16.
// ---------------------------------------------------------------------------
__global__ __launch_bounds__(256, 2) void gemm_out(
    const unsigned short* __restrict__ A,
    const unsigned short* __restrict__ B,
    const float* __restrict__ bias,
    float* __restrict__ out)
{
    __shared__ __align__(16) unsigned short As[2][128 * 32];
    __shared__ __align__(16) unsigned short Bs[2][64 * 32];

    const int tid = (int)threadIdx.x;
    const int l = tid & 63;
    const int w = tid >> 6;
    const int wm = w >> 1, wn = w & 1;
    const int m0 = blockIdx.x * 128, n0 = blockIdx.y * 64;

    const int strow = l >> 2;
    const int sslot = (l & 3) ^ ((l >> 3) & 3);
    const int fr = l & 15, fj = l >> 4;
    const int swz = ((fj ^ ((fr >> 1) & 3)) << 4);

    const f32x4 zero = {0.f, 0.f, 0.f, 0.f};
    f32x4 acc[4][2];
    #pragma unroll
    for (int mf = 0; mf < 4; ++mf)
        #pragma unroll
        for (int nf = 0; nf < 2; ++nf) acc[mf][nf] = zero;

    #pragma unroll
    for (int t = 0; t < 2; ++t) {
        const int c = w * 2 + t;
        gload16(A + (size_t)(m0 + c * 16 + strow) * DM + sslot * 8, (char*)As[0] + c * 1024);
    }
    gload16(B + (size_t)(n0 + w * 16 + strow) * DM + sslot * 8, (char*)Bs[0] + w * 1024);
    __syncthreads();

    for (int kt = 0; kt < DM; kt += 32) {
        const int cb = (kt >> 5) & 1;
        if (kt + 32 < DM) {
            #pragma unroll
            for (int t = 0; t < 2; ++t) {
                const int c = w * 2 + t;
                gload16(A + (size_t)(m0 + c * 16 + strow) * DM + (kt + 32) + sslot * 8, (char*)As[cb ^ 1] + c * 1024);
            }
            gload16(B + (size_t)(n0 + w * 16 + strow) * DM + (kt + 32) + sslot * 8, (char*)Bs[cb ^ 1] + w * 1024);
        }
        bf16x8 af[4], bfr[2];
        #pragma unroll
        for (int mf = 0; mf < 4; ++mf)
            af[mf] = *(const bf16x8*)((const char*)As[cb] + (wm * 64 + mf * 16 + fr) * 64 + swz);
        #pragma unroll
        for (int nf = 0; nf < 2; ++nf)
            bfr[nf] = *(const bf16x8*)((const char*)Bs[cb] + (wn * 32 + nf * 16 + fr) * 64 + swz);
        #pragma unroll
        for (int mf = 0; mf < 4; ++mf)
            #pragma unroll
            for (int nf = 0; nf < 2; ++nf)
                acc[mf][nf] = __builtin_amdgcn_mfma_f32_16x16x32_bf16(af[mf], bfr[nf], acc[mf][nf], 0, 0, 0);
        __syncthreads();
    }

    #pragma unroll
    for (int nf = 0; nf < 2; ++nf) {
        const int n = n0 + wn * 32 + nf * 16 + fr;
        const float bn = bias[n];
        #pragma unroll
        for (int mf = 0; mf < 4; ++mf)
            #pragma unroll
            for (int j = 0; j < 4; ++j) {
                const int m = m0 + wm * 64 + mf * 16 + fj * 4 + j;
                out[(size_t)m * DM + n] = acc[mf][nf][j] + bn;
            }
    }
}

// ---------------------------------------------------------------------------
// bf16 MFMA flash attention v5: fat waves + Q in registers.
// Block = 256 threads / 4 waves; wave owns 64 q-rows (block q-tile = 256).
// K/V fragment re-reads amortize over 2x q-rows vs v4 (LDS-BW-bound fix).
// Q regs: qreg[qf][ks] loaded once from global. Counted-vmcnt ledger as v4:
// per wave per tile 2 K-gloads (top) + 2 V-gloads (after B1); B2 waits
// vmcnt(2) = drains {V(t), K(t+1)}.
// ---------------------------------------------------------------------------
__global__ __launch_bounds__(256, 1) void attn_bf16(
    const unsigned short* __restrict__ qh,
    const unsigned short* __restrict__ kh,
    const unsigned short* __restrict__ vt,
    unsigned short* __restrict__ ao)
{
    __shared__ __align__(16) unsigned short Ks[2][64 * 64];   // [key][d]
    __shared__ __align__(16) unsigned short Vs[2][64 * 64];   // [d][key]
    __shared__ __align__(16) unsigned short Ps[256 * 64];     // [q][key]

    const int tid = (int)threadIdx.x;
    const int l = tid & 63;
    const int w = tid >> 6;
    const int bh = blockIdx.y;
    const int q0 = blockIdx.x * 256;
    const size_t pb = (size_t)bh * (SS * DK);

    const int fr = l & 15, fj = l >> 4;
    const int s8 = fr & 7;
    const int strow = l >> 3;
    const int sslot = (l & 7) ^ strow;

    // ---- Q into registers: qreg[qf][ks] covers rows w*64+qf*16+fr, d=ks*32+fj*8
    bf16x8 qreg[4][2];
    #pragma unroll
    for (int qf = 0; qf < 4; ++qf)
        #pragma unroll
        for (int ks = 0; ks < 2; ++ks)
            qreg[qf][ks] = *(const bf16x8*)(qh + pb + (size_t)(q0 + w * 64 + qf * 16 + fr) * DK + ks * 32 + fj * 8);

    // ---- stage K0, V0
    #pragma unroll
    for (int t = 0; t < 2; ++t) {
        const int c = w * 2 + t;
        gload16(kh + pb + (size_t)(c * 8 + strow) * DK + sslot * 8, (char*)Ks[0] + c * 1024);
        gload16(vt + pb + (size_t)(c * 8 + strow) * SS + sslot * 8, (char*)Vs[0] + c * 1024);
    }
    __syncthreads();

    const f32x4 zero = {0.f, 0.f, 0.f, 0.f};
    f32x4 o[4][4];      // O[q16-group][d16-group]
    f32x4 lacc[4];      // per-lane row-sum partials, q = w*64+qf*16+fr
    #pragma unroll
    for (int mf = 0; mf < 4; ++mf) {
        #pragma unroll
        for (int nf = 0; nf < 4; ++nf) o[mf][nf] = zero;
        lacc[mf] = zero;
    }

    const int NT = SS / 64;
    for (int t = 0; t < NT; ++t) {
        const int c = t & 1;
        // ---- issue K[t+1] (drains at B2(t))
        if (t + 1 < NT) {
            #pragma unroll
            for (int tt = 0; tt < 2; ++tt) {
                const int ch = w * 2 + tt;
                gload16(kh + pb + (size_t)((t + 1) * 64 + ch * 8 + strow) * DK + sslot * 8,
                        (char*)Ks[c ^ 1] + ch * 1024);
            }
        }
        // ---- scores (swapped): sc[kf][qf] = S^T, key = kf*16+fj*4+j, q-col = fr
        f32x4 sc[4][4];
        #pragma unroll
        for (int kf = 0; kf < 4; ++kf)
            #pragma unroll
            for (int qf = 0; qf < 4; ++qf) sc[kf][qf] = zero;
        __builtin_amdgcn_s_setprio(1);
        #pragma unroll
        for (int ks = 0; ks < 2; ++ks) {
            bf16x8 kfr[4];
            #pragma unroll
            for (int kf = 0; kf < 4; ++kf)
                kfr[kf] = *(const bf16x8*)((const char*)Ks[c] + (kf * 16 + fr) * 128 + (((ks * 4 + fj) ^ s8) << 4));
            #pragma unroll
            for (int kf = 0; kf < 4; ++kf)
                #pragma unroll
                for (int qf = 0; qf < 4; ++qf)
                    sc[kf][qf] = __builtin_amdgcn_mfma_f32_16x16x32_bf16(kfr[kf], qreg[qf][ks], sc[kf][qf], 0, 0, 0);
        }
        __builtin_amdgcn_s_setprio(0);

        // ---- B1: raw barrier (PV(t-1) P/V readers done; K-pf stays in flight)
        __builtin_amdgcn_sched_barrier(0);
        __builtin_amdgcn_s_barrier();
        __builtin_amdgcn_sched_barrier(0);

        // ---- issue V[t+1] (drains at B2(t+1))
        if (t + 1 < NT) {
            #pragma unroll
            for (int tt = 0; tt < 2; ++tt) {
                const int ch = w * 2 + tt;
                gload16(vt + pb + (size_t)(ch * 8 + strow) * SS + (t + 1) * 64 + sslot * 8,
                        (char*)Vs[c ^ 1] + ch * 1024);
            }
        }

        // ---- softmax: exp2 + packed bf16 store of P[q][key] (swizzled)
        #pragma unroll
        for (int qf = 0; qf < 4; ++qf) {
            const int qq = w * 64 + qf * 16 + fr;
            #pragma unroll
            for (int kf = 0; kf < 4; ++kf) {
                const float e0 = __builtin_amdgcn_exp2f(sc[kf][qf][0] + EXPC);
                const float e1 = __builtin_amdgcn_exp2f(sc[kf][qf][1] + EXPC);
                const float e2 = __builtin_amdgcn_exp2f(sc[kf][qf][2] + EXPC);
                const float e3 = __builtin_amdgcn_exp2f(sc[kf][qf][3] + EXPC);
                lacc[qf][0] += e0; lacc[qf][1] += e1;
                lacc[qf][2] += e2; lacc[qf][3] += e3;
                uint2 pw;
                pw.x = cvt_pk_bf16(e0, e1);
                pw.y = cvt_pk_bf16(e2, e3);
                *(uint2*)((char*)Ps + qq * 128 + (((2 * kf + (fj >> 1)) ^ s8) << 4) + ((fj & 1) << 3)) = pw;
            }
        }

        // ---- B2: counted drain {V[t], K[t+1]} + P visibility
        __builtin_amdgcn_sched_barrier(0);
        if (t + 1 < NT) asm volatile("s_waitcnt vmcnt(2) lgkmcnt(0)" ::: "memory");
        else            asm volatile("s_waitcnt vmcnt(0) lgkmcnt(0)" ::: "memory");
        __builtin_amdgcn_s_barrier();
        __builtin_amdgcn_sched_barrier(0);

        // ---- O += P . V
        __builtin_amdgcn_s_setprio(1);
        #pragma unroll
        for (int kp = 0; kp < 2; ++kp) {
            bf16x8 pf[4], vf[4];
            #pragma unroll
            for (int mf = 0; mf < 4; ++mf)
                pf[mf] = *(const bf16x8*)((const char*)Ps + (w * 64 + mf * 16 + fr) * 128 + (((kp * 4 + fj) ^ s8) << 4));
            #pragma unroll
            for (int nf = 0; nf < 4; ++nf)
                vf[nf] = *(const bf16x8*)((const char*)Vs[c] + (nf * 16 + fr) * 128 + (((kp * 4 + fj) ^ s8) << 4));
            #pragma unroll
            for (int mf = 0; mf < 4; ++mf)
                #pragma unroll
                for (int nf = 0; nf < 4; ++nf)
                    o[mf][nf] = __builtin_amdgcn_mfma_f32_16x16x32_bf16(pf[mf], vf[nf], o[mf][nf], 0, 0, 0);
        }
        __builtin_amdgcn_s_setprio(0);
    }

    // ---- row sums: in-lane horizontal + cross-fj reduce
    float inv[4];
    #pragma unroll
    for (int qf = 0; qf < 4; ++qf) {
        float s = (lacc[qf][0] + lacc[qf][1]) + (lacc[qf][2] + lacc[qf][3]);
        s += __shfl_xor(s, 16);
        s += __shfl_xor(s, 32);
        inv[qf] = 1.0f / s;
    }
    const int b = bh >> 4, h = bh & 15;
    #pragma unroll
    for (int mf = 0; mf < 4; ++mf) {
        float iv[4];
        #pragma unroll
        for (int j = 0; j < 4; ++j) iv[j] = __shfl(inv[mf], fj * 4 + j);
        #pragma unroll
        for (int nf = 0; nf < 4; ++nf) {
            const int d = nf * 16 + fr;
            #pragma unroll
            for (int j = 0; j < 4; ++j) {
                const int qg = q0 + w * 64 + mf * 16 + fj * 4 + j;
                ao[(size_t)(b * SS + qg) * DM + h * DK + d] = f2bf(o[mf][nf][j] * iv[j]);
            }
        }
    }
}

// ---------------------------------------------------------------------------
extern "C" void kernel_launch(void* const* d_in, const int* in_sizes, int n_in,
                              void* d_out, int out_size, void* d_ws, size_t ws_size,
                              hipStream_t stream) {
    const float* q  = (const float*)d_in[0];
    const float* k  = (const float*)d_in[1];
    const float* v  = (const float*)d_in[2];
    const float* wq = (const float*)d_in[3];
    const float* bq = (const float*)d_in[4];
    const float* wk = (const float*)d_in[5];
    const float* bk = (const float*)d_in[6];
    const float* wv = (const float*)d_in[7];
    const float* bv = (const float*)d_in[8];
    const float* wo = (const float*)d_in[9];
    const float* bo = (const float*)d_in[10];

    const size_t NQ = (size_t)MT * DM;   // 4,194,304
    const size_t NW = (size_t)DM * DM;   // 1,048,576
    unsigned short* wsb = (unsigned short*)d_ws;
    unsigned short* qb  = wsb;
    unsigned short* kb  = qb  + NQ;
    unsigned short* vb  = kb  + NQ;
    unsigned short* wqb = vb  + NQ;
    unsigned short* wkb = wqb + NW;
    unsigned short* wvb = wkb + NW;
    unsigned short* wob = wvb + NW;
    unsigned short* qhb = wob + NW;
    unsigned short* khb = qhb + NQ;
    unsigned short* vtb = khb + NQ;
    unsigned short* aob = vtb + NQ;      // ends at 32M ushort = 64 MB

    CvtArgs ca;
    ca.s[0] = q;  ca.d[0] = qb;  ca.n[0] = (int)NQ; ca.scl[0] = 1.f;
    ca.s[1] = k;  ca.d[1] = kb;  ca.n[1] = (int)NQ; ca.scl[1] = 1.f;
    ca.s[2] = v;  ca.d[2] = vb;  ca.n[2] = (int)NQ; ca.scl[2] = 1.f;
    ca.s[3] = wq; ca.d[3] = wqb; ca.n[3] = (int)NW; ca.scl[3] = QSCALE;
    ca.s[4] = wk; ca.d[4] = wkb; ca.n[4] = (int)NW; ca.scl[4] = 1.f;
    ca.s[5] = wv; ca.d[5] = wvb; ca.n[5] = (int)NW; ca.scl[5] = 1.f;
    ca.s[6] = wo; ca.d[6] = wob; ca.n[6] = (int)NW; ca.scl[6] = 1.f;
    cvt_f32_bf16<<<dim3(2048, 7), dim3(256), 0, stream>>>(ca);

    ProjArgs pa;
    pa.A[0] = qb;  pa.B[0] = wqb; pa.bias[0] = bq; pa.out[0] = qhb; pa.bscale[0] = QSCALE;
    pa.A[1] = kb;  pa.B[1] = wkb; pa.bias[1] = bk; pa.out[1] = khb; pa.bscale[1] = 1.f;
    pa.A[2] = wvb; pa.B[2] = vb;  pa.bias[2] = bv; pa.out[2] = vtb; pa.bscale[2] = 1.f;
    proj3<<<dim3(256, 3), dim3(256), 0, stream>>>(pa);

    attn_bf16<<<dim3(8, 32), dim3(256), 0, stream>>>(qhb, khb, vtb, aob);

    gemm_out<<<dim3(32, 16), dim3(256), 0, stream>>>(aob, wob, bo, (float*)d_out);
}

// Round 6
// 126.180 us; speedup vs baseline: 1.1294x; 1.1294x over previous
//
#include <hip/hip_runtime.h>

#define DM 1024
#define NH 16
#define DK 64
#define BB 2
#define SS 2048
#define MT (BB*SS)   // 4096 rows

typedef __attribute__((ext_vector_type(8))) short bf16x8;
typedef __attribute__((ext_vector_type(4))) float f32x4;

#define QSCALE 0.1803368801111191f   /* 0.125 * log2(e) */
#define EXPC  (-14.426950408889634f) /* -10 * log2(e)    */

__device__ __forceinline__ unsigned short f2bf(float f) {
    unsigned int u = __float_as_uint(f);
    u += 0x7FFF + ((u >> 16) & 1);          // round-to-nearest-even
    return (unsigned short)(u >> 16);
}

__device__ __forceinline__ unsigned int cvt_pk_bf16(float lo, float hi) {
    unsigned int r;
    asm("v_cvt_pk_bf16_f32 %0, %1, %2" : "=v"(r) : "v"(lo), "v"(hi));
    return r;
}

// K=16 bf16 MFMA (per cdna4_isa.md: v_mfma_f32_16x16x16_bf16, A/B = 2 VGPR).
// A: lane holds row l&15, k=(l>>4)*4+0..3. B: col l&15, same k. D: col l&15.
__device__ __forceinline__ void mfma16(f32x4& acc, uint2 a, uint2 b) {
    asm("v_mfma_f32_16x16x16_bf16 %0, %1, %2, %0" : "+v"(acc) : "v"(a), "v"(b));
}

// async global->LDS, 16B per lane; LDS dest is wave-uniform base + lane*16
__device__ __forceinline__ void gload16(const void* g, void* l) {
    __builtin_amdgcn_global_load_lds(
        (const __attribute__((address_space(1))) unsigned int*)g,
        (__attribute__((address_space(3))) unsigned int*)(unsigned int)(unsigned long long)l,
        16, 0, 0);
}

// ---------------------------------------------------------------------------
// fp32 -> bf16 bulk converter (with per-array scale; wq/bq absorb softmax scale)
// ---------------------------------------------------------------------------
struct CvtArgs {
    const float* s[7];
    unsigned short* d[7];
    int n[7];
    float scl[7];
};

__global__ __launch_bounds__(256) void cvt_f32_bf16(CvtArgs a) {
    const int arr = blockIdx.y;
    const int i = (blockIdx.x * 256 + threadIdx.x) * 8;
    if (i >= a.n[arr]) return;
    const float sc = a.scl[arr];
    const float4* sp = (const float4*)(a.s[arr] + i);
    float4 x = sp[0], y = sp[1];
    union { unsigned short us[8]; uint4 u4; } r;
    r.us[0] = f2bf(x.x * sc); r.us[1] = f2bf(x.y * sc);
    r.us[2] = f2bf(x.z * sc); r.us[3] = f2bf(x.w * sc);
    r.us[4] = f2bf(y.x * sc); r.us[5] = f2bf(y.y * sc);
    r.us[6] = f2bf(y.z * sc); r.us[7] = f2bf(y.w * sc);
    *(uint4*)(a.d[arr] + i) = r.u4;
}

// ---------------------------------------------------------------------------
// Merged Q/K/V projection GEMM, double-buffered staging. grid=(256,3).
// z=0: qh=(x@wq.T+bq)*QSCALE head layout; z=1: kh; z=2: vt=[bh][d][s].
// ---------------------------------------------------------------------------
struct ProjArgs {
    const unsigned short* A[3];
    const unsigned short* B[3];
    const float* bias[3];
    unsigned short* out[3];
    float bscale[3];
};

__global__ __launch_bounds__(256, 3) void proj3(ProjArgs pa) {
    __shared__ __align__(16) unsigned short As[2][128 * 32];
    __shared__ __align__(16) unsigned short Bs[2][128 * 32];

    const int z = blockIdx.y;
    const int bx = blockIdx.x;
    const int m0 = (z < 2 ? (bx >> 3) : (bx >> 5)) * 128;
    const int n0 = (z < 2 ? (bx & 7) : (bx & 31)) * 128;
    const unsigned short* A = pa.A[z];
    const unsigned short* B = pa.B[z];
    const float* bias = pa.bias[z];
    const float bsc = pa.bscale[z];
    unsigned short* out = pa.out[z];

    const int tid = (int)threadIdx.x;
    const int l = tid & 63;
    const int w = tid >> 6;
    const int wm = w >> 1, wn = w & 1;

    const int strow = l >> 2;
    const int sslot = (l & 3) ^ ((l >> 3) & 3);
    const int fr = l & 15, fj = l >> 4;
    const int swz = ((fj ^ ((fr >> 1) & 3)) << 4);

    const f32x4 zero = {0.f, 0.f, 0.f, 0.f};
    f32x4 acc[4][4];
    #pragma unroll
    for (int mf = 0; mf < 4; ++mf)
        #pragma unroll
        for (int nf = 0; nf < 4; ++nf) acc[mf][nf] = zero;

    #pragma unroll
    for (int t = 0; t < 2; ++t) {
        const int c = w * 2 + t;
        const int row = c * 16 + strow;
        gload16(A + (size_t)(m0 + row) * DM + sslot * 8, (char*)As[0] + c * 1024);
        gload16(B + (size_t)(n0 + row) * DM + sslot * 8, (char*)Bs[0] + c * 1024);
    }
    __syncthreads();

    for (int kt = 0; kt < DM; kt += 32) {
        const int cb = (kt >> 5) & 1;
        if (kt + 32 < DM) {
            #pragma unroll
            for (int t = 0; t < 2; ++t) {
                const int c = w * 2 + t;
                const int row = c * 16 + strow;
                gload16(A + (size_t)(m0 + row) * DM + (kt + 32) + sslot * 8, (char*)As[cb ^ 1] + c * 1024);
                gload16(B + (size_t)(n0 + row) * DM + (kt + 32) + sslot * 8, (char*)Bs[cb ^ 1] + c * 1024);
            }
        }
        bf16x8 af[4], bfr[4];
        #pragma unroll
        for (int mf = 0; mf < 4; ++mf)
            af[mf] = *(const bf16x8*)((const char*)As[cb] + (wm * 64 + mf * 16 + fr) * 64 + swz);
        #pragma unroll
        for (int nf = 0; nf < 4; ++nf)
            bfr[nf] = *(const bf16x8*)((const char*)Bs[cb] + (wn * 64 + nf * 16 + fr) * 64 + swz);
        #pragma unroll
        for (int mf = 0; mf < 4; ++mf)
            #pragma unroll
            for (int nf = 0; nf < 4; ++nf)
                acc[mf][nf] = __builtin_amdgcn_mfma_f32_16x16x32_bf16(af[mf], bfr[nf], acc[mf][nf], 0, 0, 0);
        __syncthreads();
    }

    #pragma unroll
    for (int nf = 0; nf < 4; ++nf) {
        const int n = n0 + wn * 64 + nf * 16 + fr;
        const float bn = (z == 2) ? 0.f : bias[n] * bsc;
        #pragma unroll
        for (int mf = 0; mf < 4; ++mf) {
            #pragma unroll
            for (int j = 0; j < 4; ++j) {
                const int m = m0 + wm * 64 + mf * 16 + fj * 4 + j;
                if (z < 2) {
                    const float val = acc[mf][nf][j] + bn;
                    out[((size_t)((m >> 11) * NH + (n >> 6)) * SS + (m & (SS - 1))) * DK + (n & 63)] = f2bf(val);
                } else {
                    const float val = acc[mf][nf][j] + bias[m];
                    out[(size_t)((n >> 11) * NH + (m >> 6)) * (SS * DK) + (size_t)(m & 63) * SS + (n & (SS - 1))] = f2bf(val);
                }
            }
        }
    }
}

// ---------------------------------------------------------------------------
// Output projection, double-buffered staging. 128x64 tile, grid 32x16.
// ---------------------------------------------------------------------------
__global__ __launch_bounds__(256, 2) void gemm_out(
    const unsigned short* __restrict__ A,
    const unsigned short* __restrict__ B,
    const float* __restrict__ bias,
    float* __restrict__ out)
{
    __shared__ __align__(16) unsigned short As[2][128 * 32];
    __shared__ __align__(16) unsigned short Bs[2][64 * 32];

    const int tid = (int)threadIdx.x;
    const int l = tid & 63;
    const int w = tid >> 6;
    const int wm = w >> 1, wn = w & 1;
    const int m0 = blockIdx.x * 128, n0 = blockIdx.y * 64;

    const int strow = l >> 2;
    const int sslot = (l & 3) ^ ((l >> 3) & 3);
    const int fr = l & 15, fj = l >> 4;
    const int swz = ((fj ^ ((fr >> 1) & 3)) << 4);

    const f32x4 zero = {0.f, 0.f, 0.f, 0.f};
    f32x4 acc[4][2];
    #pragma unroll
    for (int mf = 0; mf < 4; ++mf)
        #pragma unroll
        for (int nf = 0; nf < 2; ++nf) acc[mf][nf] = zero;

    #pragma unroll
    for (int t = 0; t < 2; ++t) {
        const int c = w * 2 + t;
        gload16(A + (size_t)(m0 + c * 16 + strow) * DM + sslot * 8, (char*)As[0] + c * 1024);
    }
    gload16(B + (size_t)(n0 + w * 16 + strow) * DM + sslot * 8, (char*)Bs[0] + w * 1024);
    __syncthreads();

    for (int kt = 0; kt < DM; kt += 32) {
        const int cb = (kt >> 5) & 1;
        if (kt + 32 < DM) {
            #pragma unroll
            for (int t = 0; t < 2; ++t) {
                const int c = w * 2 + t;
                gload16(A + (size_t)(m0 + c * 16 + strow) * DM + (kt + 32) + sslot * 8, (char*)As[cb ^ 1] + c * 1024);
            }
            gload16(B + (size_t)(n0 + w * 16 + strow) * DM + (kt + 32) + sslot * 8, (char*)Bs[cb ^ 1] + w * 1024);
        }
        bf16x8 af[4], bfr[2];
        #pragma unroll
        for (int mf = 0; mf < 4; ++mf)
            af[mf] = *(const bf16x8*)((const char*)As[cb] + (wm * 64 + mf * 16 + fr) * 64 + swz);
        #pragma unroll
        for (int nf = 0; nf < 2; ++nf)
            bfr[nf] = *(const bf16x8*)((const char*)Bs[cb] + (wn * 32 + nf * 16 + fr) * 64 + swz);
        #pragma unroll
        for (int mf = 0; mf < 4; ++mf)
            #pragma unroll
            for (int nf = 0; nf < 2; ++nf)
                acc[mf][nf] = __builtin_amdgcn_mfma_f32_16x16x32_bf16(af[mf], bfr[nf], acc[mf][nf], 0, 0, 0);
        __syncthreads();
    }

    #pragma unroll
    for (int nf = 0; nf < 2; ++nf) {
        const int n = n0 + wn * 32 + nf * 16 + fr;
        const float bn = bias[n];
        #pragma unroll
        for (int mf = 0; mf < 4; ++mf)
            #pragma unroll
            for (int j = 0; j < 4; ++j) {
                const int m = m0 + wm * 64 + mf * 16 + fj * 4 + j;
                out[(size_t)m * DM + n] = acc[mf][nf][j] + bn;
            }
    }
}

// ---------------------------------------------------------------------------
// bf16 MFMA flash attention v6: P fully in registers.
// Block = 4 waves x 32 q-rows (q-tile 128), grid (bh=32, qtile=16) so all
// q-blocks of one bh share an XCD (K/V L2-local). Q in registers.
// Swapped QK (sc = mfma(K,Q)): lane holds keys 16kf+4fj+{0..3} for q-col fr
//   == exactly the K16 MFMA B-operand layout -> PV = mfma16(V^T, pp) with NO
//   P LDS round-trip. O accumulated transposed (col=q=fr).
// One barrier + vmcnt(0) per tile (ledger in session notes):
//   t top: issue K[t+1]->Ks[c^1]   (WAR ok: Ks[c^1] readers ended < BAR(t-1))
//   QK(t) reads Ks[c]; softmax->pp (regs only)
//   BAR(t) = vmcnt(0)+s_barrier    (drains V(t) and K(t+1) for all waves)
//   issue V[t+1]->Vs[c^1]          (WAR ok: Vs[c^1] readers = PV(t-1) < BAR(t))
//   PV(t) reads Vs[c]
// ---------------------------------------------------------------------------
__global__ __launch_bounds__(256, 2) void attn_bf16(
    const unsigned short* __restrict__ qh,
    const unsigned short* __restrict__ kh,
    const unsigned short* __restrict__ vt,
    unsigned short* __restrict__ ao)
{
    __shared__ __align__(16) unsigned short Ks[2][64 * 64];   // [key][d]
    __shared__ __align__(16) unsigned short Vs[2][64 * 64];   // [d][key]

    const int tid = (int)threadIdx.x;
    const int l = tid & 63;
    const int w = tid >> 6;
    const int bh = blockIdx.x;
    const int q0 = blockIdx.y * 128;
    const size_t pb = (size_t)bh * (SS * DK);

    const int fr = l & 15, fj = l >> 4;
    const int s8 = fr & 7;
    const int strow = l >> 3;
    const int sslot = (l & 7) ^ strow;

    // ---- Q into registers: rows q = q0 + w*32 + qf*16 + fr, d = ks*32 + fj*8
    bf16x8 qreg[2][2];
    #pragma unroll
    for (int qf = 0; qf < 2; ++qf)
        #pragma unroll
        for (int ks = 0; ks < 2; ++ks)
            qreg[qf][ks] = *(const bf16x8*)(qh + pb + (size_t)(q0 + w * 32 + qf * 16 + fr) * DK + ks * 32 + fj * 8);

    // ---- stage K0, V0
    #pragma unroll
    for (int t = 0; t < 2; ++t) {
        const int c = w * 2 + t;
        gload16(kh + pb + (size_t)(c * 8 + strow) * DK + sslot * 8, (char*)Ks[0] + c * 1024);
        gload16(vt + pb + (size_t)(c * 8 + strow) * SS + sslot * 8, (char*)Vs[0] + c * 1024);
    }
    asm volatile("s_waitcnt vmcnt(0)" ::: "memory");
    __syncthreads();

    const f32x4 zero = {0.f, 0.f, 0.f, 0.f};
    f32x4 ot[4][2];     // O^T: [d16-block nf][q16-block qf], lane col q=fr, row d=fj*4+j
    f32x4 lacc[2];      // row-sum partials, q-col = fr
    #pragma unroll
    for (int nf = 0; nf < 4; ++nf)
        #pragma unroll
        for (int qf = 0; qf < 2; ++qf) ot[nf][qf] = zero;
    lacc[0] = zero; lacc[1] = zero;

    const int NT = SS / 64;
    for (int t = 0; t < NT; ++t) {
        const int c = t & 1;
        // ---- issue K[t+1]
        if (t + 1 < NT) {
            #pragma unroll
            for (int tt = 0; tt < 2; ++tt) {
                const int ch = w * 2 + tt;
                gload16(kh + pb + (size_t)((t + 1) * 64 + ch * 8 + strow) * DK + sslot * 8,
                        (char*)Ks[c ^ 1] + ch * 1024);
            }
        }
        // ---- QK (swapped): sc[kf][qf], key = 16kf + 4fj + j, q-col = fr
        f32x4 sc[4][2];
        #pragma unroll
        for (int kf = 0; kf < 4; ++kf)
            #pragma unroll
            for (int qf = 0; qf < 2; ++qf) sc[kf][qf] = zero;
        __builtin_amdgcn_s_setprio(1);
        #pragma unroll
        for (int ks = 0; ks < 2; ++ks) {
            bf16x8 kfr[4];
            #pragma unroll
            for (int kf = 0; kf < 4; ++kf)
                kfr[kf] = *(const bf16x8*)((const char*)Ks[c] + (kf * 16 + fr) * 128 + (((ks * 4 + fj) ^ s8) << 4));
            #pragma unroll
            for (int kf = 0; kf < 4; ++kf)
                #pragma unroll
                for (int qf = 0; qf < 2; ++qf)
                    sc[kf][qf] = __builtin_amdgcn_mfma_f32_16x16x32_bf16(kfr[kf], qreg[qf][ks], sc[kf][qf], 0, 0, 0);
        }
        __builtin_amdgcn_s_setprio(0);

        // ---- softmax entirely in registers -> pp (K16 B-operand fragments)
        uint2 pp[4][2];
        #pragma unroll
        for (int qf = 0; qf < 2; ++qf) {
            #pragma unroll
            for (int kf = 0; kf < 4; ++kf) {
                const float e0 = __builtin_amdgcn_exp2f(sc[kf][qf][0] + EXPC);
                const float e1 = __builtin_amdgcn_exp2f(sc[kf][qf][1] + EXPC);
                const float e2 = __builtin_amdgcn_exp2f(sc[kf][qf][2] + EXPC);
                const float e3 = __builtin_amdgcn_exp2f(sc[kf][qf][3] + EXPC);
                lacc[qf][0] += e0; lacc[qf][1] += e1;
                lacc[qf][2] += e2; lacc[qf][3] += e3;
                pp[kf][qf].x = cvt_pk_bf16(e0, e1);
                pp[kf][qf].y = cvt_pk_bf16(e2, e3);
            }
        }

        // ---- BAR(t): drain V(t) + K(t+1) for all waves
        __builtin_amdgcn_sched_barrier(0);
        asm volatile("s_waitcnt vmcnt(0) lgkmcnt(0)" ::: "memory");
        __builtin_amdgcn_s_barrier();
        __builtin_amdgcn_sched_barrier(0);

        // ---- issue V[t+1]
        if (t + 1 < NT) {
            #pragma unroll
            for (int tt = 0; tt < 2; ++tt) {
                const int ch = w * 2 + tt;
                gload16(vt + pb + (size_t)(ch * 8 + strow) * SS + (t + 1) * 64 + sslot * 8,
                        (char*)Vs[c ^ 1] + ch * 1024);
            }
        }

        // ---- PV: O^T += V^T . P^T  (K16 MFMA, A = V^T frag, B = pp)
        __builtin_amdgcn_s_setprio(1);
        #pragma unroll
        for (int kf = 0; kf < 4; ++kf) {
            #pragma unroll
            for (int nf = 0; nf < 4; ++nf) {
                const uint2 vf = *(const uint2*)((const char*)Vs[c] + (nf * 16 + fr) * 128
                                   + (((2 * kf + (fj >> 1)) ^ s8) << 4) + ((fj & 1) << 3));
                #pragma unroll
                for (int qf = 0; qf < 2; ++qf)
                    mfma16(ot[nf][qf], vf, pp[kf][qf]);
            }
        }
        __builtin_amdgcn_s_setprio(0);
    }

    // ---- row sums: in-lane horizontal + cross-fj reduce; every lane gets inv
    float inv[2];
    #pragma unroll
    for (int qf = 0; qf < 2; ++qf) {
        float s = (lacc[qf][0] + lacc[qf][1]) + (lacc[qf][2] + lacc[qf][3]);
        s += __shfl_xor(s, 16);
        s += __shfl_xor(s, 32);
        inv[qf] = 1.0f / s;
    }
    // ---- store: lane holds O[q = q0+w*32+qf*16+fr][d = nf*16+fj*4+{0..3}]
    const int b = bh >> 4, h = bh & 15;
    #pragma unroll
    for (int qf = 0; qf < 2; ++qf) {
        const int qg = q0 + w * 32 + qf * 16 + fr;
        unsigned short* dst = ao + (size_t)(b * SS + qg) * DM + h * DK + fj * 4;
        #pragma unroll
        for (int nf = 0; nf < 4; ++nf) {
            uint2 pw;
            pw.x = cvt_pk_bf16(ot[nf][qf][0] * inv[qf], ot[nf][qf][1] * inv[qf]);
            pw.y = cvt_pk_bf16(ot[nf][qf][2] * inv[qf], ot[nf][qf][3] * inv[qf]);
            *(uint2*)(dst + nf * 16) = pw;
        }
    }
}

// ---------------------------------------------------------------------------
extern "C" void kernel_launch(void* const* d_in, const int* in_sizes, int n_in,
                              void* d_out, int out_size, void* d_ws, size_t ws_size,
                              hipStream_t stream) {
    const float* q  = (const float*)d_in[0];
    const float* k  = (const float*)d_in[1];
    const float* v  = (const float*)d_in[2];
    const float* wq = (const float*)d_in[3];
    const float* bq = (const float*)d_in[4];
    const float* wk = (const float*)d_in[5];
    const float* bk = (const float*)d_in[6];
    const float* wv = (const float*)d_in[7];
    const float* bv = (const float*)d_in[8];
    const float* wo = (const float*)d_in[9];
    const float* bo = (const float*)d_in[10];

    const size_t NQ = (size_t)MT * DM;   // 4,194,304
    const size_t NW = (size_t)DM * DM;   // 1,048,576
    unsigned short* wsb = (unsigned short*)d_ws;
    unsigned short* qb  = wsb;
    unsigned short* kb  = qb  + NQ;
    unsigned short* vb  = kb  + NQ;
    unsigned short* wqb = vb  + NQ;
    unsigned short* wkb = wqb + NW;
    unsigned short* wvb = wkb + NW;
    unsigned short* wob = wvb + NW;
    unsigned short* qhb = wob + NW;
    unsigned short* khb = qhb + NQ;
    unsigned short* vtb = khb + NQ;
    unsigned short* aob = vtb + NQ;      // ends at 32M ushort = 64 MB

    CvtArgs ca;
    ca.s[0] = q;  ca.d[0] = qb;  ca.n[0] = (int)NQ; ca.scl[0] = 1.f;
    ca.s[1] = k;  ca.d[1] = kb;  ca.n[1] = (int)NQ; ca.scl[1] = 1.f;
    ca.s[2] = v;  ca.d[2] = vb;  ca.n[2] = (int)NQ; ca.scl[2] = 1.f;
    ca.s[3] = wq; ca.d[3] = wqb; ca.n[3] = (int)NW; ca.scl[3] = QSCALE;
    ca.s[4] = wk; ca.d[4] = wkb; ca.n[4] = (int)NW; ca.scl[4] = 1.f;
    ca.s[5] = wv; ca.d[5] = wvb; ca.n[5] = (int)NW; ca.scl[5] = 1.f;
    ca.s[6] = wo; ca.d[6] = wob; ca.n[6] = (int)NW; ca.scl[6] = 1.f;
    cvt_f32_bf16<<<dim3(2048, 7), dim3(256), 0, stream>>>(ca);

    ProjArgs pa;
    pa.A[0] = qb;  pa.B[0] = wqb; pa.bias[0] = bq; pa.out[0] = qhb; pa.bscale[0] = QSCALE;
    pa.A[1] = kb;  pa.B[1] = wkb; pa.bias[1] = bk; pa.out[1] = khb; pa.bscale[1] = 1.f;
    pa.A[2] = wvb; pa.B[2] = vb;  pa.bias[2] = bv; pa.out[2] = vtb; pa.bscale[2] = 1.f;
    proj3<<<dim3(256, 3), dim3(256), 0, stream>>>(pa);

    attn_bf16<<<dim3(32, 16), dim3(256), 0, stream>>>(qhb, khb, vtb, aob);

    gemm_out<<<dim3(32, 16), dim3(256), 0, stream>>>(aob, wob, bo, (float*)d_out);
}

// Round 7
// 119.018 us; speedup vs baseline: 1.1974x; 1.0602x over previous
//
#include <hip/hip_runtime.h>

#define DM 1024
#define NH 16
#define DK 64
#define BB 2
#define SS 2048
#define MT (BB*SS)   // 4096 rows

typedef __attribute__((ext_vector_type(8))) short bf16x8;
typedef __attribute__((ext_vector_type(4))) float f32x4;

#define QSCALE 0.1803368801111191f   /* 0.125 * log2(e) */
#define EXPC  (-14.426950408889634f) /* -10 * log2(e)    */

__device__ __forceinline__ unsigned short f2bf(float f) {
    unsigned int u = __float_as_uint(f);
    u += 0x7FFF + ((u >> 16) & 1);          // round-to-nearest-even
    return (unsigned short)(u >> 16);
}

__device__ __forceinline__ unsigned int cvt_pk_bf16(float lo, float hi) {
    unsigned int r;
    asm("v_cvt_pk_bf16_f32 %0, %1, %2" : "=v"(r) : "v"(lo), "v"(hi));
    return r;
}

// async global->LDS, 16B per lane; LDS dest is wave-uniform base + lane*16
__device__ __forceinline__ void gload16(const void* g, void* l) {
    __builtin_amdgcn_global_load_lds(
        (const __attribute__((address_space(1))) unsigned int*)g,
        (__attribute__((address_space(3))) unsigned int*)(unsigned int)(unsigned long long)l,
        16, 0, 0);
}

// Key-permutation within each 32-row group (applied to kh rows at proj z=1):
// position p holds key s with p = [s2, s4, s3, s1, s0] (bit permutation).
// Effect: QK^T's MFMA D-layout delivers each lane's scores already in the
// k-order required by the K32 MFMA B-operand for PV -> zero-shuffle P.
__device__ __forceinline__ int kperm(int s) {
    return (s & ~31) | (((s >> 2) & 1) << 4) | (((s >> 3) & 3) << 2) | (s & 3);
}

// ---------------------------------------------------------------------------
// fp32 -> bf16 bulk converter (with per-array scale; wq/bq absorb softmax scale)
// ---------------------------------------------------------------------------
struct CvtArgs {
    const float* s[7];
    unsigned short* d[7];
    int n[7];
    float scl[7];
};

__global__ __launch_bounds__(256) void cvt_f32_bf16(CvtArgs a) {
    const int arr = blockIdx.y;
    const int i = (blockIdx.x * 256 + threadIdx.x) * 8;
    if (i >= a.n[arr]) return;
    const float sc = a.scl[arr];
    const float4* sp = (const float4*)(a.s[arr] + i);
    float4 x = sp[0], y = sp[1];
    union { unsigned short us[8]; uint4 u4; } r;
    r.us[0] = f2bf(x.x * sc); r.us[1] = f2bf(x.y * sc);
    r.us[2] = f2bf(x.z * sc); r.us[3] = f2bf(x.w * sc);
    r.us[4] = f2bf(y.x * sc); r.us[5] = f2bf(y.y * sc);
    r.us[6] = f2bf(y.z * sc); r.us[7] = f2bf(y.w * sc);
    *(uint4*)(a.d[arr] + i) = r.u4;
}

// ---------------------------------------------------------------------------
// Merged Q/K/V projection GEMM, double-buffered staging. grid=(256,3).
// z=0: qh=(x@wq.T+bq)*QSCALE head layout; z=1: kh head layout with kperm'd
// row order; z=2: vt=[bh][d][s] (s order untouched).
// ---------------------------------------------------------------------------
struct ProjArgs {
    const unsigned short* A[3];
    const unsigned short* B[3];
    const float* bias[3];
    unsigned short* out[3];
    float bscale[3];
};

__global__ __launch_bounds__(256, 3) void proj3(ProjArgs pa) {
    __shared__ __align__(16) unsigned short As[2][128 * 32];
    __shared__ __align__(16) unsigned short Bs[2][128 * 32];

    const int z = blockIdx.y;
    const int bx = blockIdx.x;
    const int m0 = (z < 2 ? (bx >> 3) : (bx >> 5)) * 128;
    const int n0 = (z < 2 ? (bx & 7) : (bx & 31)) * 128;
    const unsigned short* A = pa.A[z];
    const unsigned short* B = pa.B[z];
    const float* bias = pa.bias[z];
    const float bsc = pa.bscale[z];
    unsigned short* out = pa.out[z];

    const int tid = (int)threadIdx.x;
    const int l = tid & 63;
    const int w = tid >> 6;
    const int wm = w >> 1, wn = w & 1;

    const int strow = l >> 2;
    const int sslot = (l & 3) ^ ((l >> 3) & 3);
    const int fr = l & 15, fj = l >> 4;
    const int swz = ((fj ^ ((fr >> 1) & 3)) << 4);

    const f32x4 zero = {0.f, 0.f, 0.f, 0.f};
    f32x4 acc[4][4];
    #pragma unroll
    for (int mf = 0; mf < 4; ++mf)
        #pragma unroll
        for (int nf = 0; nf < 4; ++nf) acc[mf][nf] = zero;

    #pragma unroll
    for (int t = 0; t < 2; ++t) {
        const int c = w * 2 + t;
        const int row = c * 16 + strow;
        gload16(A + (size_t)(m0 + row) * DM + sslot * 8, (char*)As[0] + c * 1024);
        gload16(B + (size_t)(n0 + row) * DM + sslot * 8, (char*)Bs[0] + c * 1024);
    }
    __syncthreads();

    for (int kt = 0; kt < DM; kt += 32) {
        const int cb = (kt >> 5) & 1;
        if (kt + 32 < DM) {
            #pragma unroll
            for (int t = 0; t < 2; ++t) {
                const int c = w * 2 + t;
                const int row = c * 16 + strow;
                gload16(A + (size_t)(m0 + row) * DM + (kt + 32) + sslot * 8, (char*)As[cb ^ 1] + c * 1024);
                gload16(B + (size_t)(n0 + row) * DM + (kt + 32) + sslot * 8, (char*)Bs[cb ^ 1] + c * 1024);
            }
        }
        bf16x8 af[4], bfr[4];
        #pragma unroll
        for (int mf = 0; mf < 4; ++mf)
            af[mf] = *(const bf16x8*)((const char*)As[cb] + (wm * 64 + mf * 16 + fr) * 64 + swz);
        #pragma unroll
        for (int nf = 0; nf < 4; ++nf)
            bfr[nf] = *(const bf16x8*)((const char*)Bs[cb] + (wn * 64 + nf * 16 + fr) * 64 + swz);
        #pragma unroll
        for (int mf = 0; mf < 4; ++mf)
            #pragma unroll
            for (int nf = 0; nf < 4; ++nf)
                acc[mf][nf] = __builtin_amdgcn_mfma_f32_16x16x32_bf16(af[mf], bfr[nf], acc[mf][nf], 0, 0, 0);
        __syncthreads();
    }

    #pragma unroll
    for (int nf = 0; nf < 4; ++nf) {
        const int n = n0 + wn * 64 + nf * 16 + fr;
        const float bn = (z == 2) ? 0.f : bias[n] * bsc;
        #pragma unroll
        for (int mf = 0; mf < 4; ++mf) {
            #pragma unroll
            for (int j = 0; j < 4; ++j) {
                const int m = m0 + wm * 64 + mf * 16 + fj * 4 + j;
                if (z < 2) {
                    const float val = acc[mf][nf][j] + bn;
                    int s = m & (SS - 1);
                    if (z == 1) s = kperm(s);   // permuted key-row order for attn
                    out[((size_t)((m >> 11) * NH + (n >> 6)) * SS + s) * DK + (n & 63)] = f2bf(val);
                } else {
                    const float val = acc[mf][nf][j] + bias[m];
                    out[(size_t)((n >> 11) * NH + (m >> 6)) * (SS * DK) + (size_t)(m & 63) * SS + (n & (SS - 1))] = f2bf(val);
                }
            }
        }
    }
}

// ---------------------------------------------------------------------------
// Output projection, double-buffered staging. 128x64 tile, grid 32x16.
// ---------------------------------------------------------------------------
__global__ __launch_bounds__(256, 2) void gemm_out(
    const unsigned short* __restrict__ A,
    const unsigned short* __restrict__ B,
    const float* __restrict__ bias,
    float* __restrict__ out)
{
    __shared__ __align__(16) unsigned short As[2][128 * 32];
    __shared__ __align__(16) unsigned short Bs[2][64 * 32];

    const int tid = (int)threadIdx.x;
    const int l = tid & 63;
    const int w = tid >> 6;
    const int wm = w >> 1, wn = w & 1;
    const int m0 = blockIdx.x * 128, n0 = blockIdx.y * 64;

    const int strow = l >> 2;
    const int sslot = (l & 3) ^ ((l >> 3) & 3);
    const int fr = l & 15, fj = l >> 4;
    const int swz = ((fj ^ ((fr >> 1) & 3)) << 4);

    const f32x4 zero = {0.f, 0.f, 0.f, 0.f};
    f32x4 acc[4][2];
    #pragma unroll
    for (int mf = 0; mf < 4; ++mf)
        #pragma unroll
        for (int nf = 0; nf < 2; ++nf) acc[mf][nf] = zero;

    #pragma unroll
    for (int t = 0; t < 2; ++t) {
        const int c = w * 2 + t;
        gload16(A + (size_t)(m0 + c * 16 + strow) * DM + sslot * 8, (char*)As[0] + c * 1024);
    }
    gload16(B + (size_t)(n0 + w * 16 + strow) * DM + sslot * 8, (char*)Bs[0] + w * 1024);
    __syncthreads();

    for (int kt = 0; kt < DM; kt += 32) {
        const int cb = (kt >> 5) & 1;
        if (kt + 32 < DM) {
            #pragma unroll
            for (int t = 0; t < 2; ++t) {
                const int c = w * 2 + t;
                gload16(A + (size_t)(m0 + c * 16 + strow) * DM + (kt + 32) + sslot * 8, (char*)As[cb ^ 1] + c * 1024);
            }
            gload16(B + (size_t)(n0 + w * 16 + strow) * DM + (kt + 32) + sslot * 8, (char*)Bs[cb ^ 1] + w * 1024);
        }
        bf16x8 af[4], bfr[2];
        #pragma unroll
        for (int mf = 0; mf < 4; ++mf)
            af[mf] = *(const bf16x8*)((const char*)As[cb] + (wm * 64 + mf * 16 + fr) * 64 + swz);
        #pragma unroll
        for (int nf = 0; nf < 2; ++nf)
            bfr[nf] = *(const bf16x8*)((const char*)Bs[cb] + (wn * 32 + nf * 16 + fr) * 64 + swz);
        #pragma unroll
        for (int mf = 0; mf < 4; ++mf)
            #pragma unroll
            for (int nf = 0; nf < 2; ++nf)
                acc[mf][nf] = __builtin_amdgcn_mfma_f32_16x16x32_bf16(af[mf], bfr[nf], acc[mf][nf], 0, 0, 0);
        __syncthreads();
    }

    #pragma unroll
    for (int nf = 0; nf < 2; ++nf) {
        const int n = n0 + wn * 32 + nf * 16 + fr;
        const float bn = bias[n];
        #pragma unroll
        for (int mf = 0; mf < 4; ++mf)
            #pragma unroll
            for (int j = 0; j < 4; ++j) {
                const int m = m0 + wm * 64 + mf * 16 + fj * 4 + j;
                out[(size_t)m * DM + n] = acc[mf][nf][j] + bn;
            }
    }
}

// ---------------------------------------------------------------------------
// bf16 MFMA flash attention v7: zero-shuffle K32 PV.
// kh rows are kperm'd (by proj3), so QK^T's D-layout gives each lane its 8
// B-frag keys (fj*8+0..7, true key order) lane-locally -> P packs with 16
// cvt_pk, PV = 16 mfma_16x16x32 with V A-frags as conflict-free b128 reads.
// Same sync schedule as v6 (1 barrier + vmcnt(0)/tile, K[t+1] issued at top,
// V[t+1] after barrier).
// ---------------------------------------------------------------------------
__global__ __launch_bounds__(256, 2) void attn_bf16(
    const unsigned short* __restrict__ qh,
    const unsigned short* __restrict__ kh,
    const unsigned short* __restrict__ vt,
    unsigned short* __restrict__ ao)
{
    __shared__ __align__(16) unsigned short Ks[2][64 * 64];   // [key-pos][d]
    __shared__ __align__(16) unsigned short Vs[2][64 * 64];   // [d][key]

    const int tid = (int)threadIdx.x;
    const int l = tid & 63;
    const int w = tid >> 6;
    const int bh = blockIdx.x;
    const int q0 = blockIdx.y * 128;
    const size_t pb = (size_t)bh * (SS * DK);

    const int fr = l & 15, fj = l >> 4;
    const int s8 = fr & 7;
    const int strow = l >> 3;
    const int sslot = (l & 7) ^ strow;

    // ---- Q into registers: rows q = q0 + w*32 + qf*16 + fr, d = ks*32 + fj*8
    bf16x8 qreg[2][2];
    #pragma unroll
    for (int qf = 0; qf < 2; ++qf)
        #pragma unroll
        for (int ks = 0; ks < 2; ++ks)
            qreg[qf][ks] = *(const bf16x8*)(qh + pb + (size_t)(q0 + w * 32 + qf * 16 + fr) * DK + ks * 32 + fj * 8);

    // ---- stage K0, V0
    #pragma unroll
    for (int t = 0; t < 2; ++t) {
        const int c = w * 2 + t;
        gload16(kh + pb + (size_t)(c * 8 + strow) * DK + sslot * 8, (char*)Ks[0] + c * 1024);
        gload16(vt + pb + (size_t)(c * 8 + strow) * SS + sslot * 8, (char*)Vs[0] + c * 1024);
    }
    asm volatile("s_waitcnt vmcnt(0)" ::: "memory");
    __syncthreads();

    const f32x4 zero = {0.f, 0.f, 0.f, 0.f};
    f32x4 ot[4][2];     // O^T: [d16-block nf][q16-block qf], col q=fr, row d=fj*4+j
    f32x4 lacc[2];      // row-sum partials, q-col = fr
    #pragma unroll
    for (int nf = 0; nf < 4; ++nf)
        #pragma unroll
        for (int qf = 0; qf < 2; ++qf) ot[nf][qf] = zero;
    lacc[0] = zero; lacc[1] = zero;

    const int NT = SS / 64;
    for (int t = 0; t < NT; ++t) {
        const int c = t & 1;
        // ---- issue K[t+1]
        if (t + 1 < NT) {
            #pragma unroll
            for (int tt = 0; tt < 2; ++tt) {
                const int ch = w * 2 + tt;
                gload16(kh + pb + (size_t)((t + 1) * 64 + ch * 8 + strow) * DK + sslot * 8,
                        (char*)Ks[c ^ 1] + ch * 1024);
            }
        }
        // ---- QK (swapped): sc[kf][qf]; D-pos (kf,fj,j) = true key
        //      32*(kf>>1) + fj*8 + 4*(kf&1) + j   (thanks to kperm'd kh rows)
        f32x4 sc[4][2];
        #pragma unroll
        for (int kf = 0; kf < 4; ++kf)
            #pragma unroll
            for (int qf = 0; qf < 2; ++qf) sc[kf][qf] = zero;
        __builtin_amdgcn_s_setprio(1);
        #pragma unroll
        for (int ks = 0; ks < 2; ++ks) {
            bf16x8 kfr[4];
            #pragma unroll
            for (int kf = 0; kf < 4; ++kf)
                kfr[kf] = *(const bf16x8*)((const char*)Ks[c] + (kf * 16 + fr) * 128 + (((ks * 4 + fj) ^ s8) << 4));
            #pragma unroll
            for (int kf = 0; kf < 4; ++kf)
                #pragma unroll
                for (int qf = 0; qf < 2; ++qf)
                    sc[kf][qf] = __builtin_amdgcn_mfma_f32_16x16x32_bf16(kfr[kf], qreg[qf][ks], sc[kf][qf], 0, 0, 0);
        }
        __builtin_amdgcn_s_setprio(0);

        // ---- softmax in registers -> K32 B-frags pbf[qf][ks] (zero shuffles)
        //      frag element e = key ks*32 + fj*8 + e; word m from sc[2ks+(m>>1)]
        bf16x8 pbf[2][2];
        #pragma unroll
        for (int qf = 0; qf < 2; ++qf) {
            #pragma unroll
            for (int ks = 0; ks < 2; ++ks) {
                union { unsigned int u[4]; bf16x8 v; } pk;
                #pragma unroll
                for (int kf = 0; kf < 2; ++kf) {
                    const f32x4 s4 = sc[ks * 2 + kf][qf];
                    const float e0 = __builtin_amdgcn_exp2f(s4[0] + EXPC);
                    const float e1 = __builtin_amdgcn_exp2f(s4[1] + EXPC);
                    const float e2 = __builtin_amdgcn_exp2f(s4[2] + EXPC);
                    const float e3 = __builtin_amdgcn_exp2f(s4[3] + EXPC);
                    lacc[qf][0] += e0; lacc[qf][1] += e1;
                    lacc[qf][2] += e2; lacc[qf][3] += e3;
                    pk.u[kf * 2 + 0] = cvt_pk_bf16(e0, e1);
                    pk.u[kf * 2 + 1] = cvt_pk_bf16(e2, e3);
                }
                pbf[qf][ks] = pk.v;
            }
        }

        // ---- BAR(t): drain V(t) + K(t+1) for all waves
        __builtin_amdgcn_sched_barrier(0);
        asm volatile("s_waitcnt vmcnt(0) lgkmcnt(0)" ::: "memory");
        __builtin_amdgcn_s_barrier();
        __builtin_amdgcn_sched_barrier(0);

        // ---- issue V[t+1]
        if (t + 1 < NT) {
            #pragma unroll
            for (int tt = 0; tt < 2; ++tt) {
                const int ch = w * 2 + tt;
                gload16(vt + pb + (size_t)(ch * 8 + strow) * SS + (t + 1) * 64 + sslot * 8,
                        (char*)Vs[c ^ 1] + ch * 1024);
            }
        }

        // ---- PV: O^T += V^T . P^T  (K32 MFMA; A = V^T b128, B = pbf)
        __builtin_amdgcn_s_setprio(1);
        #pragma unroll
        for (int ks = 0; ks < 2; ++ks) {
            bf16x8 va[4];
            #pragma unroll
            for (int nf = 0; nf < 4; ++nf)
                va[nf] = *(const bf16x8*)((const char*)Vs[c] + (nf * 16 + fr) * 128 + (((ks * 4 + fj) ^ s8) << 4));
            #pragma unroll
            for (int nf = 0; nf < 4; ++nf)
                #pragma unroll
                for (int qf = 0; qf < 2; ++qf)
                    ot[nf][qf] = __builtin_amdgcn_mfma_f32_16x16x32_bf16(va[nf], pbf[qf][ks], ot[nf][qf], 0, 0, 0);
        }
        __builtin_amdgcn_s_setprio(0);
    }

    // ---- row sums: in-lane horizontal + cross-fj reduce; every lane gets inv
    float inv[2];
    #pragma unroll
    for (int qf = 0; qf < 2; ++qf) {
        float s = (lacc[qf][0] + lacc[qf][1]) + (lacc[qf][2] + lacc[qf][3]);
        s += __shfl_xor(s, 16);
        s += __shfl_xor(s, 32);
        inv[qf] = 1.0f / s;
    }
    // ---- store: lane holds O[q = q0+w*32+qf*16+fr][d = nf*16+fj*4+{0..3}]
    const int b = bh >> 4, h = bh & 15;
    #pragma unroll
    for (int qf = 0; qf < 2; ++qf) {
        const int qg = q0 + w * 32 + qf * 16 + fr;
        unsigned short* dst = ao + (size_t)(b * SS + qg) * DM + h * DK + fj * 4;
        #pragma unroll
        for (int nf = 0; nf < 4; ++nf) {
            uint2 pw;
            pw.x = cvt_pk_bf16(ot[nf][qf][0] * inv[qf], ot[nf][qf][1] * inv[qf]);
            pw.y = cvt_pk_bf16(ot[nf][qf][2] * inv[qf], ot[nf][qf][3] * inv[qf]);
            *(uint2*)(dst + nf * 16) = pw;
        }
    }
}

// ---------------------------------------------------------------------------
extern "C" void kernel_launch(void* const* d_in, const int* in_sizes, int n_in,
                              void* d_out, int out_size, void* d_ws, size_t ws_size,
                              hipStream_t stream) {
    const float* q  = (const float*)d_in[0];
    const float* k  = (const float*)d_in[1];
    const float* v  = (const float*)d_in[2];
    const float* wq = (const float*)d_in[3];
    const float* bq = (const float*)d_in[4];
    const float* wk = (const float*)d_in[5];
    const float* bk = (const float*)d_in[6];
    const float* wv = (const float*)d_in[7];
    const float* bv = (const float*)d_in[8];
    const float* wo = (const float*)d_in[9];
    const float* bo = (const float*)d_in[10];

    const size_t NQ = (size_t)MT * DM;   // 4,194,304
    const size_t NW = (size_t)DM * DM;   // 1,048,576
    unsigned short* wsb = (unsigned short*)d_ws;
    unsigned short* qb  = wsb;
    unsigned short* kb  = qb  + NQ;
    unsigned short* vb  = kb  + NQ;
    unsigned short* wqb = vb  + NQ;
    unsigned short* wkb = wqb + NW;
    unsigned short* wvb = wkb + NW;
    unsigned short* wob = wvb + NW;
    unsigned short* qhb = wob + NW;
    unsigned short* khb = qhb + NQ;
    unsigned short* vtb = khb + NQ;
    unsigned short* aob = vtb + NQ;      // ends at 32M ushort = 64 MB

    CvtArgs ca;
    ca.s[0] = q;  ca.d[0] = qb;  ca.n[0] = (int)NQ; ca.scl[0] = 1.f;
    ca.s[1] = k;  ca.d[1] = kb;  ca.n[1] = (int)NQ; ca.scl[1] = 1.f;
    ca.s[2] = v;  ca.d[2] = vb;  ca.n[2] = (int)NQ; ca.scl[2] = 1.f;
    ca.s[3] = wq; ca.d[3] = wqb; ca.n[3] = (int)NW; ca.scl[3] = QSCALE;
    ca.s[4] = wk; ca.d[4] = wkb; ca.n[4] = (int)NW; ca.scl[4] = 1.f;
    ca.s[5] = wv; ca.d[5] = wvb; ca.n[5] = (int)NW; ca.scl[5] = 1.f;
    ca.s[6] = wo; ca.d[6] = wob; ca.n[6] = (int)NW; ca.scl[6] = 1.f;
    cvt_f32_bf16<<<dim3(2048, 7), dim3(256), 0, stream>>>(ca);

    ProjArgs pa;
    pa.A[0] = qb;  pa.B[0] = wqb; pa.bias[0] = bq; pa.out[0] = qhb; pa.bscale[0] = QSCALE;
    pa.A[1] = kb;  pa.B[1] = wkb; pa.bias[1] = bk; pa.out[1] = khb; pa.bscale[1] = 1.f;
    pa.A[2] = wvb; pa.B[2] = vb;  pa.bias[2] = bv; pa.out[2] = vtb; pa.bscale[2] = 1.f;
    proj3<<<dim3(256, 3), dim3(256), 0, stream>>>(pa);

    attn_bf16<<<dim3(32, 16), dim3(256), 0, stream>>>(qhb, khb, vtb, aob);

    gemm_out<<<dim3(32, 16), dim3(256), 0, stream>>>(aob, wob, bo, (float*)d_out);
}

// Round 8
// 112.449 us; speedup vs baseline: 1.2673x; 1.0584x over previous
//
#include <hip/hip_runtime.h>

#define DM 1024
#define NH 16
#define DK 64
#define BB 2
#define SS 2048
#define MT (BB*SS)   // 4096 rows

typedef __attribute__((ext_vector_type(8))) short bf16x8;
typedef __attribute__((ext_vector_type(4))) float f32x4;

#define QSCALE 0.1803368801111191f   /* 0.125 * log2(e) */
#define EXPC  (-14.426950408889634f) /* -10 * log2(e)    */

__device__ __forceinline__ unsigned short f2bf(float f) {
    unsigned int u = __float_as_uint(f);
    u += 0x7FFF + ((u >> 16) & 1);          // round-to-nearest-even
    return (unsigned short)(u >> 16);
}

__device__ __forceinline__ unsigned int cvt_pk_bf16(float lo, float hi) {
    unsigned int r;
    asm("v_cvt_pk_bf16_f32 %0, %1, %2" : "=v"(r) : "v"(lo), "v"(hi));
    return r;
}

// async global->LDS, 16B per lane; LDS dest is wave-uniform base + lane*16
__device__ __forceinline__ void gload16(const void* g, void* l) {
    __builtin_amdgcn_global_load_lds(
        (const __attribute__((address_space(1))) unsigned int*)g,
        (__attribute__((address_space(3))) unsigned int*)(unsigned int)(unsigned long long)l,
        16, 0, 0);
}

// Key-permutation within each 32-row group (applied to kh rows at proj z=1):
// position p holds key s with p = [s2, s4, s3, s1, s0] (bit permutation).
// Effect: QK^T's MFMA D-layout delivers each lane's scores already in the
// k-order required by the K32 MFMA B-operand for PV -> zero-shuffle P.
__device__ __forceinline__ int kperm(int s) {
    return (s & ~31) | (((s >> 2) & 1) << 4) | (((s >> 3) & 3) << 2) | (s & 3);
}

// ---------------------------------------------------------------------------
// fp32 -> bf16 converter, weights only now (wq scaled by QSCALE).
// ---------------------------------------------------------------------------
struct CvtArgs {
    const float* s[4];
    unsigned short* d[4];
    float scl[4];
};

__global__ __launch_bounds__(256) void cvt_f32_bf16(CvtArgs a) {
    const int arr = blockIdx.y;
    const int i = (blockIdx.x * 256 + threadIdx.x) * 8;
    const float sc = a.scl[arr];
    const float4* sp = (const float4*)(a.s[arr] + i);
    float4 x = sp[0], y = sp[1];
    union { unsigned short us[8]; uint4 u4; } r;
    r.us[0] = f2bf(x.x * sc); r.us[1] = f2bf(x.y * sc);
    r.us[2] = f2bf(x.z * sc); r.us[3] = f2bf(x.w * sc);
    r.us[4] = f2bf(y.x * sc); r.us[5] = f2bf(y.y * sc);
    r.us[6] = f2bf(y.z * sc); r.us[7] = f2bf(y.w * sc);
    *(uint4*)(a.d[arr] + i) = r.u4;
}

// ---------------------------------------------------------------------------
// Merged Q/K/V projection GEMM, XCD-swizzled blocks, fused fp32->bf16 on the
// activation operand (reg-staged: issue loads early, ds_write after MFMA).
// z=0: qh = (q@wq.T+bq)*QSCALE head layout   (A=q fp32, B=wqb bf16)
// z=1: kh head layout, kperm'd rows          (A=k fp32, B=wkb bf16)
// z=2: vt = (wv@v.T+bv) panel [bh][d][s]     (A=wvb bf16, B=v fp32)
// Block swizzle: per-XCD working set fits 4MB L2 (A 1MB + B 2MB for z<2).
// ---------------------------------------------------------------------------
struct ProjArgs {
    const void* A[3];
    const void* B[3];
    const float* bias[3];
    unsigned short* out[3];
    float bscale[3];
};

__global__ __launch_bounds__(256, 3) void proj3(ProjArgs pa) {
    __shared__ __align__(16) unsigned short As[2][128 * 32];
    __shared__ __align__(16) unsigned short Bs[2][128 * 32];

    const int z = blockIdx.y;
    const int bx = blockIdx.x;
    // XCD-aware swizzle (xcd = bx & 7 on 8-XCD round-robin, 256 % 8 == 0)
    const int xcd = bx & 7, ib = bx >> 3;
    int mb, nb;
    if (z < 2) { mb = xcd * 4 + (ib >> 3); nb = ib & 7; }     // 32 x 8
    else       { mb = ib >> 2;             nb = xcd * 4 + (ib & 3); }  // 8 x 32
    const int m0 = mb * 128, n0 = nb * 128;

    const bool a32 = (z < 2);                 // which operand is fp32
    const float* Af = (const float*)pa.A[z];
    const unsigned short* Ab = (const unsigned short*)pa.A[z];
    const float* Bf = (const float*)pa.B[z];
    const unsigned short* Bb = (const unsigned short*)pa.B[z];
    const float* bias = pa.bias[z];
    const float bsc = pa.bscale[z];
    unsigned short* out = pa.out[z];

    const int tid = (int)threadIdx.x;
    const int l = tid & 63;
    const int w = tid >> 6;
    const int wm = w >> 1, wn = w & 1;

    const int strow = l >> 2;                      // 0..15 row in chunk
    const int sslot = (l & 3) ^ ((l >> 3) & 3);    // logical 16B slot (swizzle)
    const int fr = l & 15, fj = l >> 4;
    const int swz = ((fj ^ ((fr >> 1) & 3)) << 4);

    const f32x4 zero = {0.f, 0.f, 0.f, 0.f};
    f32x4 acc[4][4];
    #pragma unroll
    for (int mf = 0; mf < 4; ++mf)
        #pragma unroll
        for (int nf = 0; nf < 4; ++nf) acc[mf][nf] = zero;

    // ---- prologue: stage kt=0 into buf 0
    #pragma unroll
    for (int t = 0; t < 2; ++t) {
        const int c = w * 2 + t;
        const int row = c * 16 + strow;
        const int col = sslot * 8;
        if (a32) {
            const float4* s = (const float4*)(Af + (size_t)(m0 + row) * DM + col);
            float4 f0 = s[0], f1 = s[1];
            union { unsigned int u[4]; bf16x8 v; } pk;
            pk.u[0] = cvt_pk_bf16(f0.x, f0.y); pk.u[1] = cvt_pk_bf16(f0.z, f0.w);
            pk.u[2] = cvt_pk_bf16(f1.x, f1.y); pk.u[3] = cvt_pk_bf16(f1.z, f1.w);
            *(bf16x8*)((char*)As[0] + c * 1024 + l * 16) = pk.v;
            gload16(Bb + (size_t)(n0 + row) * DM + col, (char*)Bs[0] + c * 1024);
        } else {
            gload16(Ab + (size_t)(m0 + row) * DM + col, (char*)As[0] + c * 1024);
            const float4* s = (const float4*)(Bf + (size_t)(n0 + row) * DM + col);
            float4 f0 = s[0], f1 = s[1];
            union { unsigned int u[4]; bf16x8 v; } pk;
            pk.u[0] = cvt_pk_bf16(f0.x, f0.y); pk.u[1] = cvt_pk_bf16(f0.z, f0.w);
            pk.u[2] = cvt_pk_bf16(f1.x, f1.y); pk.u[3] = cvt_pk_bf16(f1.z, f1.w);
            *(bf16x8*)((char*)Bs[0] + c * 1024 + l * 16) = pk.v;
        }
    }
    __syncthreads();

    for (int kt = 0; kt < DM; kt += 32) {
        const int cb = (kt >> 5) & 1;
        const bool pf = (kt + 32 < DM);
        // ---- issue next tile's loads (fp32 operand -> regs, bf16 -> gload_lds)
        float4 rf[2][2];
        if (pf) {
            #pragma unroll
            for (int t = 0; t < 2; ++t) {
                const int c = w * 2 + t;
                const int row = c * 16 + strow;
                const int col = kt + 32 + sslot * 8;
                if (a32) {
                    const float4* s = (const float4*)(Af + (size_t)(m0 + row) * DM + col);
                    rf[t][0] = s[0]; rf[t][1] = s[1];
                    gload16(Bb + (size_t)(n0 + row) * DM + col, (char*)Bs[cb ^ 1] + c * 1024);
                } else {
                    gload16(Ab + (size_t)(m0 + row) * DM + col, (char*)As[cb ^ 1] + c * 1024);
                    const float4* s = (const float4*)(Bf + (size_t)(n0 + row) * DM + col);
                    rf[t][0] = s[0]; rf[t][1] = s[1];
                }
            }
        }
        // ---- MFMA on current buffer
        bf16x8 af[4], bfr[4];
        #pragma unroll
        for (int mf = 0; mf < 4; ++mf)
            af[mf] = *(const bf16x8*)((const char*)As[cb] + (wm * 64 + mf * 16 + fr) * 64 + swz);
        #pragma unroll
        for (int nf = 0; nf < 4; ++nf)
            bfr[nf] = *(const bf16x8*)((const char*)Bs[cb] + (wn * 64 + nf * 16 + fr) * 64 + swz);
        #pragma unroll
        for (int mf = 0; mf < 4; ++mf)
            #pragma unroll
            for (int nf = 0; nf < 4; ++nf)
                acc[mf][nf] = __builtin_amdgcn_mfma_f32_16x16x32_bf16(af[mf], bfr[nf], acc[mf][nf], 0, 0, 0);
        // ---- late write of the converted fp32 operand into the next buffer
        if (pf) {
            #pragma unroll
            for (int t = 0; t < 2; ++t) {
                const int c = w * 2 + t;
                union { unsigned int u[4]; bf16x8 v; } pk;
                pk.u[0] = cvt_pk_bf16(rf[t][0].x, rf[t][0].y);
                pk.u[1] = cvt_pk_bf16(rf[t][0].z, rf[t][0].w);
                pk.u[2] = cvt_pk_bf16(rf[t][1].x, rf[t][1].y);
                pk.u[3] = cvt_pk_bf16(rf[t][1].z, rf[t][1].w);
                if (a32) *(bf16x8*)((char*)As[cb ^ 1] + c * 1024 + l * 16) = pk.v;
                else     *(bf16x8*)((char*)Bs[cb ^ 1] + c * 1024 + l * 16) = pk.v;
            }
        }
        __syncthreads();
    }

    #pragma unroll
    for (int nf = 0; nf < 4; ++nf) {
        const int n = n0 + wn * 64 + nf * 16 + fr;
        const float bn = (z == 2) ? 0.f : bias[n] * bsc;
        #pragma unroll
        for (int mf = 0; mf < 4; ++mf) {
            #pragma unroll
            for (int j = 0; j < 4; ++j) {
                const int m = m0 + wm * 64 + mf * 16 + fj * 4 + j;
                if (z < 2) {
                    const float val = acc[mf][nf][j] + bn;
                    int s = m & (SS - 1);
                    if (z == 1) s = kperm(s);   // permuted key-row order for attn
                    out[((size_t)((m >> 11) * NH + (n >> 6)) * SS + s) * DK + (n & 63)] = f2bf(val);
                } else {
                    const float val = acc[mf][nf][j] + bias[m];
                    out[(size_t)((n >> 11) * NH + (m >> 6)) * (SS * DK) + (size_t)(m & 63) * SS + (n & (SS - 1))] = f2bf(val);
                }
            }
        }
    }
}

// ---------------------------------------------------------------------------
// Output projection, double-buffered staging. 128x64 tile, grid 32x16.
// (natural mapping is already XCD-friendly: all 16 n-blocks of an m-block
//  share xcd = bx%8; wo fits every L2.)
// ---------------------------------------------------------------------------
__global__ __launch_bounds__(256, 2) void gemm_out(
    const unsigned short* __restrict__ A,
    const unsigned short* __restrict__ B,
    const float* __restrict__ bias,
    float* __restrict__ out)
{
    __shared__ __align__(16) unsigned short As[2][128 * 32];
    __shared__ __align__(16) unsigned short Bs[2][64 * 32];

    const int tid = (int)threadIdx.x;
    const int l = tid & 63;
    const int w = tid >> 6;
    const int wm = w >> 1, wn = w & 1;
    const int m0 = blockIdx.x * 128, n0 = blockIdx.y * 64;

    const int strow = l >> 2;
    const int sslot = (l & 3) ^ ((l >> 3) & 3);
    const int fr = l & 15, fj = l >> 4;
    const int swz = ((fj ^ ((fr >> 1) & 3)) << 4);

    const f32x4 zero = {0.f, 0.f, 0.f, 0.f};
    f32x4 acc[4][2];
    #pragma unroll
    for (int mf = 0; mf < 4; ++mf)
        #pragma unroll
        for (int nf = 0; nf < 2; ++nf) acc[mf][nf] = zero;

    #pragma unroll
    for (int t = 0; t < 2; ++t) {
        const int c = w * 2 + t;
        gload16(A + (size_t)(m0 + c * 16 + strow) * DM + sslot * 8, (char*)As[0] + c * 1024);
    }
    gload16(B + (size_t)(n0 + w * 16 + strow) * DM + sslot * 8, (char*)Bs[0] + w * 1024);
    __syncthreads();

    for (int kt = 0; kt < DM; kt += 32) {
        const int cb = (kt >> 5) & 1;
        if (kt + 32 < DM) {
            #pragma unroll
            for (int t = 0; t < 2; ++t) {
                const int c = w * 2 + t;
                gload16(A + (size_t)(m0 + c * 16 + strow) * DM + (kt + 32) + sslot * 8, (char*)As[cb ^ 1] + c * 1024);
            }
            gload16(B + (size_t)(n0 + w * 16 + strow) * DM + (kt + 32) + sslot * 8, (char*)Bs[cb ^ 1] + w * 1024);
        }
        bf16x8 af[4], bfr[2];
        #pragma unroll
        for (int mf = 0; mf < 4; ++mf)
            af[mf] = *(const bf16x8*)((const char*)As[cb] + (wm * 64 + mf * 16 + fr) * 64 + swz);
        #pragma unroll
        for (int nf = 0; nf < 2; ++nf)
            bfr[nf] = *(const bf16x8*)((const char*)Bs[cb] + (wn * 32 + nf * 16 + fr) * 64 + swz);
        #pragma unroll
        for (int mf = 0; mf < 4; ++mf)
            #pragma unroll
            for (int nf = 0; nf < 2; ++nf)
                acc[mf][nf] = __builtin_amdgcn_mfma_f32_16x16x32_bf16(af[mf], bfr[nf], acc[mf][nf], 0, 0, 0);
        __syncthreads();
    }

    #pragma unroll
    for (int nf = 0; nf < 2; ++nf) {
        const int n = n0 + wn * 32 + nf * 16 + fr;
        const float bn = bias[n];
        #pragma unroll
        for (int mf = 0; mf < 4; ++mf)
            #pragma unroll
            for (int j = 0; j < 4; ++j) {
                const int m = m0 + wm * 64 + mf * 16 + fj * 4 + j;
                out[(size_t)m * DM + n] = acc[mf][nf][j] + bn;
            }
    }
}

// ---------------------------------------------------------------------------
// bf16 MFMA flash attention (v7, unchanged): zero-shuffle K32 PV via kperm'd
// kh rows; Q in regs; 1 barrier + vmcnt(0)/tile; bh-major grid for XCD L2.
// ---------------------------------------------------------------------------
__global__ __launch_bounds__(256, 2) void attn_bf16(
    const unsigned short* __restrict__ qh,
    const unsigned short* __restrict__ kh,
    const unsigned short* __restrict__ vt,
    unsigned short* __restrict__ ao)
{
    __shared__ __align__(16) unsigned short Ks[2][64 * 64];   // [key-pos][d]
    __shared__ __align__(16) unsigned short Vs[2][64 * 64];   // [d][key]

    const int tid = (int)threadIdx.x;
    const int l = tid & 63;
    const int w = tid >> 6;
    const int bh = blockIdx.x;
    const int q0 = blockIdx.y * 128;
    const size_t pb = (size_t)bh * (SS * DK);

    const int fr = l & 15, fj = l >> 4;
    const int s8 = fr & 7;
    const int strow = l >> 3;
    const int sslot = (l & 7) ^ strow;

    bf16x8 qreg[2][2];
    #pragma unroll
    for (int qf = 0; qf < 2; ++qf)
        #pragma unroll
        for (int ks = 0; ks < 2; ++ks)
            qreg[qf][ks] = *(const bf16x8*)(qh + pb + (size_t)(q0 + w * 32 + qf * 16 + fr) * DK + ks * 32 + fj * 8);

    #pragma unroll
    for (int t = 0; t < 2; ++t) {
        const int c = w * 2 + t;
        gload16(kh + pb + (size_t)(c * 8 + strow) * DK + sslot * 8, (char*)Ks[0] + c * 1024);
        gload16(vt + pb + (size_t)(c * 8 + strow) * SS + sslot * 8, (char*)Vs[0] + c * 1024);
    }
    asm volatile("s_waitcnt vmcnt(0)" ::: "memory");
    __syncthreads();

    const f32x4 zero = {0.f, 0.f, 0.f, 0.f};
    f32x4 ot[4][2];
    f32x4 lacc[2];
    #pragma unroll
    for (int nf = 0; nf < 4; ++nf)
        #pragma unroll
        for (int qf = 0; qf < 2; ++qf) ot[nf][qf] = zero;
    lacc[0] = zero; lacc[1] = zero;

    const int NT = SS / 64;
    for (int t = 0; t < NT; ++t) {
        const int c = t & 1;
        if (t + 1 < NT) {
            #pragma unroll
            for (int tt = 0; tt < 2; ++tt) {
                const int ch = w * 2 + tt;
                gload16(kh + pb + (size_t)((t + 1) * 64 + ch * 8 + strow) * DK + sslot * 8,
                        (char*)Ks[c ^ 1] + ch * 1024);
            }
        }
        f32x4 sc[4][2];
        #pragma unroll
        for (int kf = 0; kf < 4; ++kf)
            #pragma unroll
            for (int qf = 0; qf < 2; ++qf) sc[kf][qf] = zero;
        __builtin_amdgcn_s_setprio(1);
        #pragma unroll
        for (int ks = 0; ks < 2; ++ks) {
            bf16x8 kfr[4];
            #pragma unroll
            for (int kf = 0; kf < 4; ++kf)
                kfr[kf] = *(const bf16x8*)((const char*)Ks[c] + (kf * 16 + fr) * 128 + (((ks * 4 + fj) ^ s8) << 4));
            #pragma unroll
            for (int kf = 0; kf < 4; ++kf)
                #pragma unroll
                for (int qf = 0; qf < 2; ++qf)
                    sc[kf][qf] = __builtin_amdgcn_mfma_f32_16x16x32_bf16(kfr[kf], qreg[qf][ks], sc[kf][qf], 0, 0, 0);
        }
        __builtin_amdgcn_s_setprio(0);

        bf16x8 pbf[2][2];
        #pragma unroll
        for (int qf = 0; qf < 2; ++qf) {
            #pragma unroll
            for (int ks = 0; ks < 2; ++ks) {
                union { unsigned int u[4]; bf16x8 v; } pk;
                #pragma unroll
                for (int kf = 0; kf < 2; ++kf) {
                    const f32x4 s4 = sc[ks * 2 + kf][qf];
                    const float e0 = __builtin_amdgcn_exp2f(s4[0] + EXPC);
                    const float e1 = __builtin_amdgcn_exp2f(s4[1] + EXPC);
                    const float e2 = __builtin_amdgcn_exp2f(s4[2] + EXPC);
                    const float e3 = __builtin_amdgcn_exp2f(s4[3] + EXPC);
                    lacc[qf][0] += e0; lacc[qf][1] += e1;
                    lacc[qf][2] += e2; lacc[qf][3] += e3;
                    pk.u[kf * 2 + 0] = cvt_pk_bf16(e0, e1);
                    pk.u[kf * 2 + 1] = cvt_pk_bf16(e2, e3);
                }
                pbf[qf][ks] = pk.v;
            }
        }

        __builtin_amdgcn_sched_barrier(0);
        asm volatile("s_waitcnt vmcnt(0) lgkmcnt(0)" ::: "memory");
        __builtin_amdgcn_s_barrier();
        __builtin_amdgcn_sched_barrier(0);

        if (t + 1 < NT) {
            #pragma unroll
            for (int tt = 0; tt < 2; ++tt) {
                const int ch = w * 2 + tt;
                gload16(vt + pb + (size_t)(ch * 8 + strow) * SS + (t + 1) * 64 + sslot * 8,
                        (char*)Vs[c ^ 1] + ch * 1024);
            }
        }

        __builtin_amdgcn_s_setprio(1);
        #pragma unroll
        for (int ks = 0; ks < 2; ++ks) {
            bf16x8 va[4];
            #pragma unroll
            for (int nf = 0; nf < 4; ++nf)
                va[nf] = *(const bf16x8*)((const char*)Vs[c] + (nf * 16 + fr) * 128 + (((ks * 4 + fj) ^ s8) << 4));
            #pragma unroll
            for (int nf = 0; nf < 4; ++nf)
                #pragma unroll
                for (int qf = 0; qf < 2; ++qf)
                    ot[nf][qf] = __builtin_amdgcn_mfma_f32_16x16x32_bf16(va[nf], pbf[qf][ks], ot[nf][qf], 0, 0, 0);
        }
        __builtin_amdgcn_s_setprio(0);
    }

    float inv[2];
    #pragma unroll
    for (int qf = 0; qf < 2; ++qf) {
        float s = (lacc[qf][0] + lacc[qf][1]) + (lacc[qf][2] + lacc[qf][3]);
        s += __shfl_xor(s, 16);
        s += __shfl_xor(s, 32);
        inv[qf] = 1.0f / s;
    }
    const int b = bh >> 4, h = bh & 15;
    #pragma unroll
    for (int qf = 0; qf < 2; ++qf) {
        const int qg = q0 + w * 32 + qf * 16 + fr;
        unsigned short* dst = ao + (size_t)(b * SS + qg) * DM + h * DK + fj * 4;
        #pragma unroll
        for (int nf = 0; nf < 4; ++nf) {
            uint2 pw;
            pw.x = cvt_pk_bf16(ot[nf][qf][0] * inv[qf], ot[nf][qf][1] * inv[qf]);
            pw.y = cvt_pk_bf16(ot[nf][qf][2] * inv[qf], ot[nf][qf][3] * inv[qf]);
            *(uint2*)(dst + nf * 16) = pw;
        }
    }
}

// ---------------------------------------------------------------------------
extern "C" void kernel_launch(void* const* d_in, const int* in_sizes, int n_in,
                              void* d_out, int out_size, void* d_ws, size_t ws_size,
                              hipStream_t stream) {
    const float* q  = (const float*)d_in[0];
    const float* k  = (const float*)d_in[1];
    const float* v  = (const float*)d_in[2];
    const float* wq = (const float*)d_in[3];
    const float* bq = (const float*)d_in[4];
    const float* wk = (const float*)d_in[5];
    const float* bk = (const float*)d_in[6];
    const float* wv = (const float*)d_in[7];
    const float* bv = (const float*)d_in[8];
    const float* wo = (const float*)d_in[9];
    const float* bo = (const float*)d_in[10];

    const size_t NQ = (size_t)MT * DM;   // 4,194,304
    const size_t NW = (size_t)DM * DM;   // 1,048,576
    unsigned short* wsb = (unsigned short*)d_ws;
    unsigned short* wqb = wsb;
    unsigned short* wkb = wqb + NW;
    unsigned short* wvb = wkb + NW;
    unsigned short* wob = wvb + NW;
    unsigned short* qhb = wob + NW;
    unsigned short* khb = qhb + NQ;
    unsigned short* vtb = khb + NQ;
    unsigned short* aob = vtb + NQ;      // ends at 20M ushort = 40 MB

    CvtArgs ca;
    ca.s[0] = wq; ca.d[0] = wqb; ca.scl[0] = QSCALE;
    ca.s[1] = wk; ca.d[1] = wkb; ca.scl[1] = 1.f;
    ca.s[2] = wv; ca.d[2] = wvb; ca.scl[2] = 1.f;
    ca.s[3] = wo; ca.d[3] = wob; ca.scl[3] = 1.f;
    cvt_f32_bf16<<<dim3(512, 4), dim3(256), 0, stream>>>(ca);

    ProjArgs pa;
    pa.A[0] = q;   pa.B[0] = wqb; pa.bias[0] = bq; pa.out[0] = qhb; pa.bscale[0] = QSCALE;
    pa.A[1] = k;   pa.B[1] = wkb; pa.bias[1] = bk; pa.out[1] = khb; pa.bscale[1] = 1.f;
    pa.A[2] = wvb; pa.B[2] = v;   pa.bias[2] = bv; pa.out[2] = vtb; pa.bscale[2] = 1.f;
    proj3<<<dim3(256, 3), dim3(256), 0, stream>>>(pa);

    attn_bf16<<<dim3(32, 16), dim3(256), 0, stream>>>(qhb, khb, vtb, aob);

    gemm_out<<<dim3(32, 16), dim3(256), 0, stream>>>(aob, wob, bo, (float*)d_out);
}